// Round 15
// baseline (465.501 us; speedup 1.0000x reference)
//
#include <hip/hip_runtime.h>

#define Hd 128
#define NTOT 65536
#define RREL 4
#define NRSEG (NTOT*RREL)
#define NEDGE 524288

typedef unsigned short u16;
typedef unsigned int u32;
typedef short bf16x8 __attribute__((ext_vector_type(8)));
typedef float f32x4 __attribute__((ext_vector_type(4)));

__device__ __forceinline__ u16 f2bf(float f) {   // RNE
  u32 u = __float_as_uint(f);
  return (u16)((u + 0x7fffu + ((u >> 16) & 1u)) >> 16);
}
__device__ __forceinline__ u32 pack2(float lo, float hi) {
  return ((u32)f2bf(hi) << 16) | f2bf(lo);
}

// swizzled byte offset within a [rows][256 B] bf16 LDS tile (involution on bits 7:4)
__device__ __forceinline__ int swzb(int row, int o) {
  return (row*256 + o) ^ ((row & 15) << 4);
}

// ======== mgemm: C[M,128] = A[M,K] @ Bt[128,K]^T (128-row tiles, 256 thr) ========
__device__ __forceinline__ void stage_tile(const u16* __restrict__ g, int ld,
                                           u16* lds, int wave, int lane) {
#pragma unroll
  for (int t = 0; t < 2; ++t) {
    int i = wave*2 + t;
    int row = i*16 + (lane >> 2);
    int col16 = (lane & 3) ^ ((lane >> 3) & 3);
    const u16* src = g + (size_t)row*ld + col16*8;
    __builtin_amdgcn_global_load_lds((const __attribute__((address_space(1))) void*)src,
                                     (__attribute__((address_space(3))) void*)(lds + i*512),
                                     16, 0, 0);
  }
}

// CMODE 2: remapped final-output write (+bias);
// CMODE 3: dual half-M (blocks >= gridDim/2 use A+32768 rows, Bt+128*128, bias2, C+32768 rows)
template<int CMODE>
__global__ __launch_bounds__(256) void mgemm(const u16* __restrict__ A, int lda,
                                             const u16* __restrict__ Bt, int ldb,
                                             const float* __restrict__ bias,
                                             const float* __restrict__ bias2,
                                             float* __restrict__ C, int kTot)
{
  __shared__ u16 As[4096], Bs[4096];
  const int tid = threadIdx.x, wave = tid >> 6, lane = tid & 63;
  const int wm = wave >> 1, wn = wave & 1;
  int bx = blockIdx.x;
  if (CMODE == 3) {
    if (bx >= (int)gridDim.x/2) {
      bx -= gridDim.x/2;
      A += (size_t)32768*lda; Bt += 128*128; bias = bias2; C += (size_t)32768*Hd;
    }
  }
  const int brow = bx * 128;
  const u16* Ab = A + (size_t)brow*lda;
  f32x4 acc[4][4];
#pragma unroll
  for (int i = 0; i < 4; ++i)
#pragma unroll
    for (int j = 0; j < 4; ++j) acc[i][j] = (f32x4){0.f, 0.f, 0.f, 0.f};

  const int ks = (lane >> 4) * 16;
  const int rl = lane & 15;
  for (int k0 = 0; k0 < kTot; k0 += 32) {
    stage_tile(Ab + k0, lda, As, wave, lane);
    stage_tile(Bt + k0, ldb, Bs, wave, lane);
    __syncthreads();
    bf16x8 af[4], bv[4];
    const char* Ac = (const char*)As;
    const char* Bc = (const char*)Bs;
#pragma unroll
    for (int i = 0; i < 4; ++i) {
      int r = wm*64 + i*16 + rl;
      int by = (r*64 + ks) ^ (((r >> 1) & 3) << 4);
      af[i] = *(const bf16x8*)(Ac + by);
    }
#pragma unroll
    for (int j = 0; j < 4; ++j) {
      int r = wn*64 + j*16 + rl;
      int by = (r*64 + ks) ^ (((r >> 1) & 3) << 4);
      bv[j] = *(const bf16x8*)(Bc + by);
    }
#pragma unroll
    for (int i = 0; i < 4; ++i)
#pragma unroll
      for (int j = 0; j < 4; ++j)
        acc[i][j] = __builtin_amdgcn_mfma_f32_16x16x32_bf16(af[i], bv[j], acc[i][j], 0, 0, 0);
    __syncthreads();
  }
  const int cl = lane & 15;
  const int rq = (lane >> 4) * 4;
#pragma unroll
  for (int i = 0; i < 4; ++i) {
#pragma unroll
    for (int q = 0; q < 4; ++q) {
      int row = brow + wm*64 + i*16 + rq + q;
      size_t ob;
      if (CMODE == 2) {
        int b = row >> 6, p = row & 63;
        ob = (p == 0) ? (size_t)b*Hd
                      : (size_t)(1024*Hd) + ((size_t)(b*63 + (p-1)))*Hd;
      } else {
        ob = (size_t)row * Hd;
      }
#pragma unroll
      for (int j = 0; j < 4; ++j) {
        int col = wn*64 + j*16 + cl;
        float v = acc[i][j][q];
        if (bias) v += bias[col];
        C[ob + col] = v;
      }
    }
  }
}

// ======== fused register-gather + K=1152 GEMM + BN-stats (64-row tile, 48 KB) ========
// meta[e] = src | (bf16(alpha) << 16)  (alpha pre-normalized by seg_alpha)
// Btg: bf16 [128 out][1152], chunks: 0..3 conv_rel r, 4..7 attW r, 8 conv_root
__device__ __forceinline__ void stageB(const u16* __restrict__ gbase, int ld,
                                       u16* lds, int wave, int lane) {
#pragma unroll
  for (int t = 0; t < 4; ++t) {
    int ti = wave*4 + t;
    int row = ti*4 + (lane >> 4);
    int lchunk = (lane & 15) ^ (row & 15);
    const u16* src = gbase + (size_t)row*ld + lchunk*8;
    __builtin_amdgcn_global_load_lds((const __attribute__((address_space(1))) void*)src,
                                     (__attribute__((address_space(3))) void*)(lds + ti*512),
                                     16, 0, 0);
  }
}
// stage 64 rows x 256B (16 KB) with 8 waves
__device__ __forceinline__ void stageY64(const u16* __restrict__ gbase, int ld,
                                         u16* lds, int wave, int lane) {
#pragma unroll
  for (int t = 0; t < 2; ++t) {
    int ti = wave*2 + t;
    int row = ti*4 + (lane >> 4);
    int lchunk = (lane & 15) ^ (row & 15);
    const u16* src = gbase + (size_t)row*ld + lchunk*8;
    __builtin_amdgcn_global_load_lds((const __attribute__((address_space(1))) void*)src,
                                     (__attribute__((address_space(3))) void*)(lds + ti*512),
                                     16, 0, 0);
  }
}

__device__ __forceinline__ void mfma64(const u16* Yt, const u16* Bt, f32x4 (&acc)[2][2],
                                       int wm, int wn, int lane) {
  const int rl = lane & 15;
  const int ko = (lane >> 4) * 16;
  const char* Yc_ = (const char*)Yt;
  const char* Bc_ = (const char*)Bt;
#pragma unroll
  for (int ks = 0; ks < 4; ++ks) {
    int o = ks*64 + ko;
    bf16x8 af[2], bv[2];
#pragma unroll
    for (int i = 0; i < 2; ++i)
      af[i] = *(const bf16x8*)(Yc_ + swzb(wm*32 + i*16 + rl, o));
#pragma unroll
    for (int j = 0; j < 2; ++j)
      bv[j] = *(const bf16x8*)(Bc_ + swzb(wn*32 + j*16 + rl, o));
#pragma unroll
    for (int i = 0; i < 2; ++i)
#pragma unroll
      for (int j = 0; j < 2; ++j)
        acc[i][j] = __builtin_amdgcn_mfma_f32_16x16x32_bf16(af[i], bv[j], acc[i][j], 0, 0, 0);
  }
}

__global__ __launch_bounds__(512, 4) void fused_gemm(
    const u16* __restrict__ xmb, const u32* __restrict__ meta,
    const int* __restrict__ offsets, const u16* __restrict__ Btg,
    float* __restrict__ hbuf, float* __restrict__ bns)
{
  __shared__ u16 Yt[8192];    // 16 KB: 64-row Y tile
  __shared__ u16 Bw[16384];   // 32 KB: 128-row weight tile
  const int tid = threadIdx.x, wave = tid >> 6, lane = tid & 63;
  const int wm = wave >> 2, wn = wave & 3;
  const int brow = blockIdx.x * 64;
  f32x4 acc[2][2];
#pragma unroll
  for (int i = 0; i < 2; ++i)
#pragma unroll
    for (int j = 0; j < 2; ++j) acc[i][j] = (f32x4){0.f,0.f,0.f,0.f};

  u32 axp[8];                 // att sums, packed bf16

  for (int r = 0; r < RREL; ++r) {
    const int segBase = (r << 16) + brow;      // rel-major segments
    __syncthreads();                           // Yt/Bw free (prev mfma done)
    stageB(Btg + r*128, 1152, Bw, wave, lane); // conv weights in flight during gather
#pragma unroll
    for (int g = 0; g < 4; ++g) {              // 4 groups x 2 nodes per wave
      int ln0 = wave*8 + g*2;
#pragma unroll
      for (int m = 0; m < 2; ++m) {            // sequential: bounds register pressure
        int seg = segBase + ln0 + m;
        int e0 = offsets[seg];
        int ct = offsets[seg+1] - e0;
        u32 mm[8];                             // src | alpha-bf16<<16 (broadcast)
#pragma unroll
        for (int k = 0; k < 8; ++k)
          mm[k] = meta[e0 + k];                // padded; junk if k>=ct
        u32 uu[8];
#pragma unroll
        for (int k = 0; k < 8; ++k) {
          int sx = (k < ct) ? (int)(mm[k] & 0xffffu) : 0;   // clamp to L1-hot row
          uu[k] = *(const u32*)(xmb + ((size_t)sx << 7) + lane*2);
        }
        float cx = 0.f, cy = 0.f, ax = 0.f, ay = 0.f;
#pragma unroll
        for (int k = 0; k < 8; ++k) {
          float pr = (k < ct) ? 1.f : 0.f;
          float al = pr * __uint_as_float(mm[k] & 0xffff0000u);  // bf16 alpha
          float vx = __uint_as_float(uu[k] << 16);
          float vy = __uint_as_float(uu[k] & 0xffff0000u);
          cx = fmaf(pr, vx, cx);
          cy = fmaf(pr, vy, cy);
          ax = fmaf(al, vx, ax);
          ay = fmaf(al, vy, ay);
        }
        for (int e = e0 + 8; e < e0 + ct; ++e) {   // ultra-rare tail (P~2e-4)
          u32 m2 = meta[e];
          int s = (int)(m2 & 0xffffu);
          float al = __uint_as_float(m2 & 0xffff0000u);
          u32 u = *(const u32*)(xmb + ((size_t)s << 7) + lane*2);
          float vx = __uint_as_float(u << 16);
          float vy = __uint_as_float(u & 0xffff0000u);
          cx += vx; cy += vy;
          ax = fmaf(al, vx, ax);
          ay = fmaf(al, vy, ay);
        }
        int ln = ln0 + m;
        float ic = 1.f / (float)max(ct, 1);
        *(u32*)((char*)Yt + swzb(ln, lane*4)) = pack2(cx*ic, cy*ic);
        axp[g*2+m] = pack2(ax, ay);
      }
    }
    __syncthreads();                           // Y conv written + conv B staged
    mfma64(Yt, Bw, acc, wm, wn, lane);         // conv contribution
    __syncthreads();                           // conv reads done
    stageB(Btg + (4+r)*128, 1152, Bw, wave, lane);   // att weights
#pragma unroll
    for (int g = 0; g < 4; ++g)
#pragma unroll
      for (int m = 0; m < 2; ++m) {
        int ln = wave*8 + g*2 + m;
        *(u32*)((char*)Yt + swzb(ln, lane*4)) = axp[g*2+m];
      }
    __syncthreads();                           // Y att written + att B staged
    mfma64(Yt, Bw, acc, wm, wn, lane);         // att contribution
  }
  // ---- root chunk: Y = xmb tile ----
  __syncthreads();
  stageY64(xmb + ((size_t)brow << 7), Hd, Yt, wave, lane);
  stageB(Btg + 8*128, 1152, Bw, wave, lane);
  __syncthreads();
  mfma64(Yt, Bw, acc, wm, wn, lane);

  // ---- epilogue: write hbuf + BN partial sums ----
  const int cl = lane & 15, rq = (lane >> 4) * 4;
#pragma unroll
  for (int j = 0; j < 2; ++j) {
    float s = 0.f, s2 = 0.f;
#pragma unroll
    for (int i = 0; i < 2; ++i) {
#pragma unroll
      for (int q = 0; q < 4; ++q) {
        float v = acc[i][j][q];
        int row = brow + wm*32 + i*16 + rq + q;
        hbuf[(size_t)row*Hd + wn*32 + j*16 + cl] = v;
        s += v; s2 = fmaf(v, v, s2);
      }
    }
    s  += __shfl_xor(s, 16);  s  += __shfl_xor(s, 32);
    s2 += __shfl_xor(s2, 16); s2 += __shfl_xor(s2, 32);
    if (lane < 16) {
      int col = wn*32 + j*16 + cl;
      unsafeAtomicAdd(&bns[col], s);
      unsafeAtomicAdd(&bns[128 + col], s2);
    }
  }
}

// ---------------- all weight transpose+convert in one dispatch ----------------
__global__ void wtrans_all(const float* __restrict__ conv_rel, const float* __restrict__ attW,
                           const float* __restrict__ conv_root, const float* __restrict__ W0,
                           const float* __restrict__ W1, const float* __restrict__ fcW,
                           u16* __restrict__ Btg0, u16* __restrict__ Btg1, u16* __restrict__ Btw) {
  int idx = blockIdx.x*256 + threadIdx.x;
  if (idx < 294912) {
    int l = idx / 147456;
    int rem = idx - l*147456;
    u16* Btg = l ? Btg1 : Btg0;
    float v; int o, kk;
    if (rem < 65536)       { o = rem & 127; kk = rem >> 7;               v = conv_rel[(size_t)l*65536 + rem]; }
    else if (rem < 131072) { int r2 = rem - 65536; o = r2 & 127; kk = 512 + (r2 >> 7); v = attW[(size_t)l*262144 + r2]; }
    else                   { int r3 = rem - 131072; o = r3 & 127; kk = 1024 + (r3 >> 7); v = conv_root[(size_t)l*16384 + r3]; }
    Btg[(size_t)o*1152 + kk] = f2bf(v);
  } else {
    int rem = idx - 294912;
    int w = rem >> 14, r3 = rem & 16383;
    int k = r3 >> 7, o = r3 & 127;
    const float* sp = (w == 0) ? W0 : (w == 1 ? W1 : fcW);
    Btw[w*16384 + o*128 + k] = f2bf(sp[r3]);
  }
}

// ---------------- small utility kernels ----------------
__global__ void fill_i32(int* p, int v, int n) {
  int i = blockIdx.x*blockDim.x + threadIdx.x;
  if (i < n) p[i] = v;
}
__global__ void edge_count(const int* __restrict__ dst, const int* __restrict__ et, int* __restrict__ cnt) {
  int e = blockIdx.x*blockDim.x + threadIdx.x;
  if (e < NEDGE) atomicAdd(&cnt[(et[e] << 16) + dst[e]], 1);
}
__global__ void cvt_bf16_2(const float* __restrict__ s0, const float* __restrict__ s1,
                           u16* __restrict__ dst) {
  int i = blockIdx.x*256 + threadIdx.x;
  const int half = 32768*Hd/4;
  const float* s = (i < half) ? s0 : s1;
  int ii = (i < half) ? i : i - half;
  float4 v = *reinterpret_cast<const float4*>(s + (size_t)ii*4);
  *reinterpret_cast<uint2*>(dst + (size_t)i*4) = make_uint2(pack2(v.x, v.y), pack2(v.z, v.w));
}

// ---------------- CSR build (rel-major segments: seg = (et<<16)|dst) ----------------
__global__ void scan1_k(const int* __restrict__ cnt, int* __restrict__ partial, int* __restrict__ bsum) {
  __shared__ int sh[256];
  int t = threadIdx.x;
  int i = blockIdx.x*256 + t;
  int v = cnt[i];
  sh[t] = v; __syncthreads();
  for (int off = 1; off < 256; off <<= 1) {
    int u = (t >= off) ? sh[t-off] : 0;
    __syncthreads();
    sh[t] += u;
    __syncthreads();
  }
  partial[i] = sh[t] - v;
  if (t == 255) bsum[blockIdx.x] = sh[255];
}
__global__ void scan2_k(int* __restrict__ bsum) {
  __shared__ int sh[256];
  int t = threadIdx.x;
  int v0 = bsum[t*4+0], v1 = bsum[t*4+1], v2 = bsum[t*4+2], v3 = bsum[t*4+3];
  int tot = v0+v1+v2+v3;
  sh[t] = tot; __syncthreads();
  for (int off = 1; off < 256; off <<= 1) {
    int u = (t >= off) ? sh[t-off] : 0;
    __syncthreads();
    sh[t] += u;
    __syncthreads();
  }
  int base = sh[t] - tot;
  bsum[t*4+0] = base;
  bsum[t*4+1] = base + v0;
  bsum[t*4+2] = base + v0+v1;
  bsum[t*4+3] = base + v0+v1+v2;
}
__global__ void scan3_k(const int* __restrict__ partial, const int* __restrict__ bsum, int* __restrict__ offsets) {
  int i = blockIdx.x*256 + threadIdx.x;
  offsets[i] = partial[i] + bsum[i >> 8];
  if (i == 0) offsets[NRSEG] = NEDGE;
}
__global__ void csr_fill(const int* __restrict__ src, const int* __restrict__ dst,
                         const int* __restrict__ et, const int* __restrict__ offsets,
                         int* __restrict__ fillctr, u32* __restrict__ meta) {
  int e = blockIdx.x*blockDim.x + threadIdx.x;
  if (e >= NEDGE) return;
  int d = dst[e];
  int seg = (et[e] << 16) + d;
  int pos = offsets[seg] + atomicAdd(&fillctr[seg], 1);
  meta[pos] = (u32)src[e];          // high bits filled with alpha by seg_alpha
}

// ---------------- attention scalar path ----------------
__global__ void qkvec_all(const float* __restrict__ attW, const float* __restrict__ att_q,
                          const float* __restrict__ att_k,
                          float* __restrict__ qvecL, float* __restrict__ kvecL) {
  int l = blockIdx.x;
  const float* aW = attW + (size_t)l*16*Hd*Hd;
  const float* aq = att_q + (size_t)l*16*Hd;
  const float* ak = att_k + (size_t)l*16*Hd;
  int r = threadIdx.x >> 7, h = threadIdx.x & 127;
  const float* wrow = aW + ((size_t)r*Hd + h)*Hd;
  const float* qv = aq + (size_t)r*Hd;
  const float* kv = ak + (size_t)r*Hd;
  float sq_ = 0.f, sk_ = 0.f;
  for (int o = 0; o < Hd; ++o) { float w = wrow[o]; sq_ = fmaf(w, qv[o], sq_); sk_ = fmaf(w, kv[o], sk_); }
  qvecL[l*512 + r*Hd + h] = sq_;
  kvecL[l*512 + r*Hd + h] = sk_;
}

// one wave per node: produce xmb (bf16) AND per-rel attention scalars sq/sk.
// MODE 0: xb = rm * x_in; MODE 1: xb = rm * leaky(bn(h)); MODE 2: xb = leaky(bn(h)) + x_in
template<int MODE>
__global__ __launch_bounds__(256) void xform_sqk(
    const float* __restrict__ hin, const float* __restrict__ scale,
    const float* __restrict__ shift, const float* __restrict__ mask,
    const float* __restrict__ x_in, const float* __restrict__ qvec,
    const float* __restrict__ kvec, u16* __restrict__ xmb,
    float* __restrict__ sq, float* __restrict__ sk)
{
  int n = blockIdx.x*4 + (threadIdx.x >> 6);
  int lane = threadIdx.x & 63;
  float2 v = *(const float2*)(hin + (size_t)n*Hd + lane*2);
  if (MODE != 0) {
    float2 sc = *(const float2*)(scale + lane*2);
    float2 sh = *(const float2*)(shift + lane*2);
    v.x = fmaf(v.x, sc.x, sh.x); v.y = fmaf(v.y, sc.y, sh.y);
    v.x = v.x >= 0.f ? v.x : 0.01f*v.x;
    v.y = v.y >= 0.f ? v.y : 0.01f*v.y;
  }
  float2 xb;
  if (MODE == 2) {
    float2 rs = *(const float2*)(x_in + (size_t)n*Hd + lane*2);
    xb.x = v.x + rs.x; xb.y = v.y + rs.y;
  } else {
    float s = mask[(size_t)n*Hd];          // row-constant mask
    xb.x = v.x*s; xb.y = v.y*s;
  }
  *(u32*)(xmb + (size_t)n*Hd + lane*2) = pack2(xb.x, xb.y);
  if (MODE != 2) {
    float pq[RREL], pk[RREL];
#pragma unroll
    for (int r = 0; r < RREL; ++r) {
      float2 q = *(const float2*)(qvec + r*Hd + lane*2);
      float2 k = *(const float2*)(kvec + r*Hd + lane*2);
      pq[r] = xb.x*q.x + xb.y*q.y;
      pk[r] = xb.x*k.x + xb.y*k.y;
    }
#pragma unroll
    for (int off = 32; off > 0; off >>= 1)
#pragma unroll
      for (int r = 0; r < RREL; ++r) {
        pq[r] += __shfl_xor(pq[r], off);
        pk[r] += __shfl_xor(pk[r], off);
      }
    if (lane == 0)
#pragma unroll
      for (int r = 0; r < RREL; ++r) {
        sq[(size_t)r*NTOT + n] = pq[r];
        sk[(size_t)r*NTOT + n] = pk[r];
      }
  }
}

// one thread per segment: softmax within segment (logits bounded -> no max-subtract).
// pass 1: store bf16(exp) in meta high bits, sum in f32; pass 2: rescale in place.
// Block 0 zeroes bns.
__global__ void seg_alpha(u32* __restrict__ meta, const int* __restrict__ offsets,
                          const float* __restrict__ sq, const float* __restrict__ sk,
                          float* __restrict__ bns) {
  if (blockIdx.x == 0) bns[threadIdx.x] = 0.f;
  int seg = blockIdx.x*256 + threadIdx.x;
  int e0 = offsets[seg], e1 = offsets[seg+1];
  if (e0 == e1) return;
  const float* skr = sk + (seg & 0xFFFF0000u);   // + r*NTOT
  float sqv = sq[seg];
  float sum = 0.f;
  for (int e = e0; e < e1; ++e) {
    u32 m = meta[e];
    float lg = sqv + skr[m & 0xffffu];
    lg = lg >= 0.f ? lg : 0.2f*lg;
    float ex = __expf(lg);
    sum += ex;
    meta[e] = (m & 0xffffu) | ((u32)f2bf(ex) << 16);
  }
  float inv = 1.f / fmaxf(sum, 1e-16f);
  for (int e = e0; e < e1; ++e) {
    u32 m = meta[e];
    float a = __uint_as_float(m & 0xffff0000u) * inv;
    meta[e] = (m & 0xffffu) | ((u32)f2bf(a) << 16);
  }
}

// ---------------- batchnorm finalize (and zero bns for next layer) ----------------
__global__ void bn_final(float* __restrict__ bns, const float* __restrict__ g,
                         const float* __restrict__ b, float* __restrict__ scale,
                         float* __restrict__ shift) {
  int c = threadIdx.x;
  float s1 = bns[c], s2 = bns[128 + c];
  bns[c] = 0.f; bns[128 + c] = 0.f;
  float mu = s1 * (1.f/NTOT);
  float var = s2 * (1.f/NTOT) - mu*mu;
  float sc = g[c] / sqrtf(var + 1e-5f);
  scale[c] = sc;
  shift[c] = b[c] - mu*sc;
}

extern "C" void kernel_launch(void* const* d_in, const int* in_sizes, int n_in,
                              void* d_out, int out_size, void* d_ws, size_t ws_size,
                              hipStream_t stream) {
  const float* x0       = (const float*)d_in[0];
  const float* x1       = (const float*)d_in[1];
  const float* W0       = (const float*)d_in[2];
  const float* b0       = (const float*)d_in[3];
  const float* W1       = (const float*)d_in[4];
  const float* b1       = (const float*)d_in[5];
  const float* mask     = (const float*)d_in[6];
  const float* conv_root= (const float*)d_in[7];
  const float* conv_rel = (const float*)d_in[8];
  const float* attW     = (const float*)d_in[10];
  const float* att_q    = (const float*)d_in[11];
  const float* att_k    = (const float*)d_in[12];
  const float* bn_g     = (const float*)d_in[14];
  const float* bn_b     = (const float*)d_in[15];
  const float* fc_W     = (const float*)d_in[16];
  const float* fc_b     = (const float*)d_in[17];
  const int* edge_index = (const int*)d_in[18];
  const int* edge_type  = (const int*)d_in[19];
  const int* src = edge_index;
  const int* dst = edge_index + NEDGE;
  (void)in_sizes; (void)n_in; (void)out_size; (void)ws_size;

  char* ws = (char*)d_ws;
  size_t off = 0;
  auto alloc = [&](size_t bytes) { void* p = ws + off; off = (off + bytes + 255) & ~(size_t)255; return p; };
  float* x_in  = (float*)alloc((size_t)NTOT*Hd*4);
  float* hbuf  = (float*)alloc((size_t)NTOT*Hd*4);
  u16*   xmb   = (u16*)  alloc((size_t)NTOT*Hd*2);
  float* sq    = (float*)alloc((size_t)RREL*NTOT*4);
  float* sk    = (float*)alloc((size_t)RREL*NTOT*4);
  int* cnt     = (int*)alloc((size_t)NRSEG*4);
  int* fillctr = (int*)alloc((size_t)NRSEG*4);    // contiguous with cnt
  int* partial = (int*)alloc((size_t)NRSEG*4);
  int* offsets = (int*)alloc((size_t)(NRSEG+4)*4);
  int* bsum    = (int*)alloc(4096);
  u32* meta    = (u32*)alloc((size_t)(NEDGE+16)*4);     // +16 pad for head over-read
  float* qvecL = (float*)alloc(2*512*4);
  float* kvecL = (float*)alloc(2*512*4);
  float* bns    = (float*)alloc(1024);
  float* bnscale= (float*)alloc(512);
  float* bnshift= (float*)alloc(512);
  u16* Btw  = (u16*)alloc((size_t)3*128*128*2);   // W0^T | W1^T | fc^T
  u16* Btg0 = (u16*)alloc((size_t)128*1152*2);
  u16* Btg1 = (u16*)alloc((size_t)128*1152*2);
  u16* BtgL[2] = {Btg0, Btg1};

  // ---- static CSR (rel-major segments) ----
  fill_i32<<<2*NRSEG/256, 256, 0, stream>>>(cnt, 0, 2*NRSEG);   // cnt + fillctr
  edge_count<<<NEDGE/256, 256, 0, stream>>>(dst, edge_type, cnt);
  scan1_k<<<NRSEG/256, 256, 0, stream>>>(cnt, partial, bsum);
  scan2_k<<<1, 256, 0, stream>>>(bsum);
  scan3_k<<<NRSEG/256, 256, 0, stream>>>(partial, bsum, offsets);
  csr_fill<<<NEDGE/256, 256, 0, stream>>>(src, dst, edge_type, offsets, fillctr, meta);

  // ---- all weights transposed/converted in one dispatch; qvec/kvec both layers ----
  wtrans_all<<<1344, 256, 0, stream>>>(conv_rel, attW, conv_root, W0, W1, fc_W,
                                       Btg0, Btg1, Btw);
  qkvec_all<<<2, 512, 0, stream>>>(attW, att_q, att_k, qvecL, kvecL);

  // ---- x_in = [x0@W0+b0 ; x1@W1+b1]; xmb = bf16(rm*x_in) + sq/sk(layer0) ----
  cvt_bf16_2<<<(NTOT*Hd/4)/256, 256, 0, stream>>>(x0, x1, xmb);
  mgemm<3><<<512, 256, 0, stream>>>(xmb, Hd, Btw, 128, b0, b1, x_in, 128);
  xform_sqk<0><<<NTOT/4, 256, 0, stream>>>(x_in, nullptr, nullptr, mask, nullptr,
                                           qvecL, kvecL, xmb, sq, sk);

  for (int l = 0; l < 2; ++l) {
    seg_alpha<<<NRSEG/256, 256, 0, stream>>>(meta, offsets, sq, sk, bns);
    fused_gemm<<<NTOT/64, 512, 0, stream>>>(xmb, meta, offsets, BtgL[l], hbuf, bns);
    bn_final<<<1, 128, 0, stream>>>(bns, bn_g + (size_t)l*Hd, bn_b + (size_t)l*Hd, bnscale, bnshift);
    if (l == 0)
      xform_sqk<1><<<NTOT/4, 256, 0, stream>>>(hbuf, bnscale, bnshift, mask, nullptr,
                                               qvecL + 512, kvecL + 512, xmb, sq, sk);
    else
      xform_sqk<2><<<NTOT/4, 256, 0, stream>>>(hbuf, bnscale, bnshift, nullptr, x_in,
                                               nullptr, nullptr, xmb, sq, sk);
  }

  // out = (x + x_in) @ fc_W + fc_b, remapped rows
  mgemm<2><<<512, 256, 0, stream>>>(xmb, Hd, Btw + 2*16384, 128, fc_b, nullptr,
                                    (float*)d_out, 128);
}

// Round 16
// 425.883 us; speedup vs baseline: 1.0930x; 1.0930x over previous
//
#include <hip/hip_runtime.h>

#define Hd 128
#define NTOT 65536
#define RREL 4
#define NRSEG (NTOT*RREL)
#define NEDGE 524288

typedef unsigned short u16;
typedef unsigned int u32;
typedef short bf16x8 __attribute__((ext_vector_type(8)));
typedef float f32x4 __attribute__((ext_vector_type(4)));

__device__ __forceinline__ u16 f2bf(float f) {   // RNE
  u32 u = __float_as_uint(f);
  return (u16)((u + 0x7fffu + ((u >> 16) & 1u)) >> 16);
}
__device__ __forceinline__ u32 pack2(float lo, float hi) {
  return ((u32)f2bf(hi) << 16) | f2bf(lo);
}

// swizzled byte offset within a [rows][256 B] bf16 LDS tile (involution on bits 7:4)
__device__ __forceinline__ int swzb(int row, int o) {
  return (row*256 + o) ^ ((row & 15) << 4);
}

// ======== mgemm: C[M,128] = A[M,K] @ Bt[128,K]^T (128-row tiles, 256 thr) ========
__device__ __forceinline__ void stage_tile(const u16* __restrict__ g, int ld,
                                           u16* lds, int wave, int lane) {
#pragma unroll
  for (int t = 0; t < 2; ++t) {
    int i = wave*2 + t;
    int row = i*16 + (lane >> 2);
    int col16 = (lane & 3) ^ ((lane >> 3) & 3);
    const u16* src = g + (size_t)row*ld + col16*8;
    __builtin_amdgcn_global_load_lds((const __attribute__((address_space(1))) void*)src,
                                     (__attribute__((address_space(3))) void*)(lds + i*512),
                                     16, 0, 0);
  }
}

// CMODE 2: remapped final-output write (+bias);
// CMODE 3: dual half-M (blocks >= gridDim/2 use A+32768 rows, Bt+128*128, bias2, C+32768 rows)
template<int CMODE>
__global__ __launch_bounds__(256) void mgemm(const u16* __restrict__ A, int lda,
                                             const u16* __restrict__ Bt, int ldb,
                                             const float* __restrict__ bias,
                                             const float* __restrict__ bias2,
                                             float* __restrict__ C, int kTot)
{
  __shared__ u16 As[4096], Bs[4096];
  const int tid = threadIdx.x, wave = tid >> 6, lane = tid & 63;
  const int wm = wave >> 1, wn = wave & 1;
  int bx = blockIdx.x;
  if (CMODE == 3) {
    if (bx >= (int)gridDim.x/2) {
      bx -= gridDim.x/2;
      A += (size_t)32768*lda; Bt += 128*128; bias = bias2; C += (size_t)32768*Hd;
    }
  }
  const int brow = bx * 128;
  const u16* Ab = A + (size_t)brow*lda;
  f32x4 acc[4][4];
#pragma unroll
  for (int i = 0; i < 4; ++i)
#pragma unroll
    for (int j = 0; j < 4; ++j) acc[i][j] = (f32x4){0.f, 0.f, 0.f, 0.f};

  const int ks = (lane >> 4) * 16;
  const int rl = lane & 15;
  for (int k0 = 0; k0 < kTot; k0 += 32) {
    stage_tile(Ab + k0, lda, As, wave, lane);
    stage_tile(Bt + k0, ldb, Bs, wave, lane);
    __syncthreads();
    bf16x8 af[4], bv[4];
    const char* Ac = (const char*)As;
    const char* Bc = (const char*)Bs;
#pragma unroll
    for (int i = 0; i < 4; ++i) {
      int r = wm*64 + i*16 + rl;
      int by = (r*64 + ks) ^ (((r >> 1) & 3) << 4);
      af[i] = *(const bf16x8*)(Ac + by);
    }
#pragma unroll
    for (int j = 0; j < 4; ++j) {
      int r = wn*64 + j*16 + rl;
      int by = (r*64 + ks) ^ (((r >> 1) & 3) << 4);
      bv[j] = *(const bf16x8*)(Bc + by);
    }
#pragma unroll
    for (int i = 0; i < 4; ++i)
#pragma unroll
      for (int j = 0; j < 4; ++j)
        acc[i][j] = __builtin_amdgcn_mfma_f32_16x16x32_bf16(af[i], bv[j], acc[i][j], 0, 0, 0);
    __syncthreads();
  }
  const int cl = lane & 15;
  const int rq = (lane >> 4) * 4;
#pragma unroll
  for (int i = 0; i < 4; ++i) {
#pragma unroll
    for (int q = 0; q < 4; ++q) {
      int row = brow + wm*64 + i*16 + rq + q;
      size_t ob;
      if (CMODE == 2) {
        int b = row >> 6, p = row & 63;
        ob = (p == 0) ? (size_t)b*Hd
                      : (size_t)(1024*Hd) + ((size_t)(b*63 + (p-1)))*Hd;
      } else {
        ob = (size_t)row * Hd;
      }
#pragma unroll
      for (int j = 0; j < 4; ++j) {
        int col = wn*64 + j*16 + cl;
        float v = acc[i][j][q];
        if (bias) v += bias[col];
        C[ob + col] = v;
      }
    }
  }
}

// ======== fused register-gather + K=1152 GEMM + BN-stats (64-row tile, 48 KB) ========
// meta[e] = src | (bf16(alpha) << 16)  (alpha pre-normalized by seg_alpha)
// Btg: bf16 [128 out][1152], chunks: 0..3 conv_rel r, 4..7 attW r, 8 conv_root
__device__ __forceinline__ void stageB(const u16* __restrict__ gbase, int ld,
                                       u16* lds, int wave, int lane) {
#pragma unroll
  for (int t = 0; t < 4; ++t) {
    int ti = wave*4 + t;
    int row = ti*4 + (lane >> 4);
    int lchunk = (lane & 15) ^ (row & 15);
    const u16* src = gbase + (size_t)row*ld + lchunk*8;
    __builtin_amdgcn_global_load_lds((const __attribute__((address_space(1))) void*)src,
                                     (__attribute__((address_space(3))) void*)(lds + ti*512),
                                     16, 0, 0);
  }
}
// stage 64 rows x 256B (16 KB) with 8 waves
__device__ __forceinline__ void stageY64(const u16* __restrict__ gbase, int ld,
                                         u16* lds, int wave, int lane) {
#pragma unroll
  for (int t = 0; t < 2; ++t) {
    int ti = wave*2 + t;
    int row = ti*4 + (lane >> 4);
    int lchunk = (lane & 15) ^ (row & 15);
    const u16* src = gbase + (size_t)row*ld + lchunk*8;
    __builtin_amdgcn_global_load_lds((const __attribute__((address_space(1))) void*)src,
                                     (__attribute__((address_space(3))) void*)(lds + ti*512),
                                     16, 0, 0);
  }
}

__device__ __forceinline__ void mfma64(const u16* Yt, const u16* Bt, f32x4 (&acc)[2][2],
                                       int wm, int wn, int lane) {
  const int rl = lane & 15;
  const int ko = (lane >> 4) * 16;
  const char* Yc_ = (const char*)Yt;
  const char* Bc_ = (const char*)Bt;
#pragma unroll
  for (int ks = 0; ks < 4; ++ks) {
    int o = ks*64 + ko;
    bf16x8 af[2], bv[2];
#pragma unroll
    for (int i = 0; i < 2; ++i)
      af[i] = *(const bf16x8*)(Yc_ + swzb(wm*32 + i*16 + rl, o));
#pragma unroll
    for (int j = 0; j < 2; ++j)
      bv[j] = *(const bf16x8*)(Bc_ + swzb(wn*32 + j*16 + rl, o));
#pragma unroll
    for (int i = 0; i < 2; ++i)
#pragma unroll
      for (int j = 0; j < 2; ++j)
        acc[i][j] = __builtin_amdgcn_mfma_f32_16x16x32_bf16(af[i], bv[j], acc[i][j], 0, 0, 0);
  }
}

__global__ __launch_bounds__(512, 4) void fused_gemm(
    const u16* __restrict__ xmb, const u32* __restrict__ meta,
    const int* __restrict__ offsets, const u16* __restrict__ Btg,
    float* __restrict__ hbuf, float* __restrict__ bns)
{
  __shared__ u16 Yt[8192];    // 16 KB: 64-row Y tile
  __shared__ u16 Bw[16384];   // 32 KB: 128-row weight tile
  const int tid = threadIdx.x, wave = tid >> 6, lane = tid & 63;
  const int wm = wave >> 2, wn = wave & 3;
  const int brow = blockIdx.x * 64;
  f32x4 acc[2][2];
#pragma unroll
  for (int i = 0; i < 2; ++i)
#pragma unroll
    for (int j = 0; j < 2; ++j) acc[i][j] = (f32x4){0.f,0.f,0.f,0.f};

  u32 axp[8];                 // att sums, packed bf16

  for (int r = 0; r < RREL; ++r) {
    const int segBase = (r << 16) + brow;      // rel-major segments
    __syncthreads();                           // Yt/Bw free (prev mfma done)
    stageB(Btg + r*128, 1152, Bw, wave, lane); // conv weights in flight during gather
#pragma unroll
    for (int g = 0; g < 4; ++g) {              // 4 groups x 2 nodes per wave
      int ln0 = wave*8 + g*2;
      int e0[2], ct[2];
#pragma unroll
      for (int m = 0; m < 2; ++m) {
        int seg = segBase + ln0 + m;
        e0[m] = offsets[seg];
        ct[m] = offsets[seg+1] - e0[m];
      }
      u32 mm[2][4];                            // src | alpha-bf16<<16 (broadcast loads)
#pragma unroll
      for (int m = 0; m < 2; ++m)
#pragma unroll
        for (int k = 0; k < 4; ++k)
          mm[m][k] = meta[e0[m] + k];          // padded; junk if k>=ct
      u32 uu[2][4];
#pragma unroll
      for (int m = 0; m < 2; ++m)
#pragma unroll
        for (int k = 0; k < 4; ++k) {
          int sx = (k < ct[m]) ? (int)(mm[m][k] & 0xffffu) : 0;   // clamp to L1-hot row
          uu[m][k] = *(const u32*)(xmb + ((size_t)sx << 7) + lane*2);
        }
      float cx[2], cy[2], ax[2], ay[2];
#pragma unroll
      for (int m = 0; m < 2; ++m) { cx[m]=cy[m]=ax[m]=ay[m]=0.f; }
#pragma unroll
      for (int m = 0; m < 2; ++m) {
#pragma unroll
        for (int k = 0; k < 4; ++k) {
          float pr = (k < ct[m]) ? 1.f : 0.f;
          float al = pr * __uint_as_float(mm[m][k] & 0xffff0000u);  // bf16 alpha
          float vx = __uint_as_float(uu[m][k] << 16);
          float vy = __uint_as_float(uu[m][k] & 0xffff0000u);
          cx[m] = fmaf(pr, vx, cx[m]);
          cy[m] = fmaf(pr, vy, cy[m]);
          ax[m] = fmaf(al, vx, ax[m]);
          ay[m] = fmaf(al, vy, ay[m]);
        }
        for (int e = e0[m] + 4; e < e0[m] + ct[m]; ++e) {   // rare tail
          u32 m2 = meta[e];
          int s = (int)(m2 & 0xffffu);
          float al = __uint_as_float(m2 & 0xffff0000u);
          u32 u = *(const u32*)(xmb + ((size_t)s << 7) + lane*2);
          float vx = __uint_as_float(u << 16);
          float vy = __uint_as_float(u & 0xffff0000u);
          cx[m] += vx; cy[m] += vy;
          ax[m] = fmaf(al, vx, ax[m]);
          ay[m] = fmaf(al, vy, ay[m]);
        }
      }
#pragma unroll
      for (int m = 0; m < 2; ++m) {
        int ln = ln0 + m;
        float ic = 1.f / (float)max(ct[m], 1);
        *(u32*)((char*)Yt + swzb(ln, lane*4)) = pack2(cx[m]*ic, cy[m]*ic);
        axp[g*2+m] = pack2(ax[m], ay[m]);
      }
    }
    __syncthreads();                           // Y conv written + conv B staged
    mfma64(Yt, Bw, acc, wm, wn, lane);         // conv contribution
    __syncthreads();                           // conv reads done
    stageB(Btg + (4+r)*128, 1152, Bw, wave, lane);   // att weights
#pragma unroll
    for (int g = 0; g < 4; ++g)
#pragma unroll
      for (int m = 0; m < 2; ++m) {
        int ln = wave*8 + g*2 + m;
        *(u32*)((char*)Yt + swzb(ln, lane*4)) = axp[g*2+m];
      }
    __syncthreads();                           // Y att written + att B staged
    mfma64(Yt, Bw, acc, wm, wn, lane);         // att contribution
  }
  // ---- root chunk: Y = xmb tile ----
  __syncthreads();
  stageY64(xmb + ((size_t)brow << 7), Hd, Yt, wave, lane);
  stageB(Btg + 8*128, 1152, Bw, wave, lane);
  __syncthreads();
  mfma64(Yt, Bw, acc, wm, wn, lane);

  // ---- epilogue: write hbuf + BN partial sums ----
  const int cl = lane & 15, rq = (lane >> 4) * 4;
#pragma unroll
  for (int j = 0; j < 2; ++j) {
    float s = 0.f, s2 = 0.f;
#pragma unroll
    for (int i = 0; i < 2; ++i) {
#pragma unroll
      for (int q = 0; q < 4; ++q) {
        float v = acc[i][j][q];
        int row = brow + wm*32 + i*16 + rq + q;
        hbuf[(size_t)row*Hd + wn*32 + j*16 + cl] = v;
        s += v; s2 = fmaf(v, v, s2);
      }
    }
    s  += __shfl_xor(s, 16);  s  += __shfl_xor(s, 32);
    s2 += __shfl_xor(s2, 16); s2 += __shfl_xor(s2, 32);
    if (lane < 16) {
      int col = wn*32 + j*16 + cl;
      unsafeAtomicAdd(&bns[col], s);
      unsafeAtomicAdd(&bns[128 + col], s2);
    }
  }
}

// ---------------- all weight transpose+convert in one dispatch ----------------
__global__ void wtrans_all(const float* __restrict__ conv_rel, const float* __restrict__ attW,
                           const float* __restrict__ conv_root, const float* __restrict__ W0,
                           const float* __restrict__ W1, const float* __restrict__ fcW,
                           u16* __restrict__ Btg0, u16* __restrict__ Btg1, u16* __restrict__ Btw) {
  int idx = blockIdx.x*256 + threadIdx.x;
  if (idx < 294912) {
    int l = idx / 147456;
    int rem = idx - l*147456;
    u16* Btg = l ? Btg1 : Btg0;
    float v; int o, kk;
    if (rem < 65536)       { o = rem & 127; kk = rem >> 7;               v = conv_rel[(size_t)l*65536 + rem]; }
    else if (rem < 131072) { int r2 = rem - 65536; o = r2 & 127; kk = 512 + (r2 >> 7); v = attW[(size_t)l*262144 + r2]; }
    else                   { int r3 = rem - 131072; o = r3 & 127; kk = 1024 + (r3 >> 7); v = conv_root[(size_t)l*16384 + r3]; }
    Btg[(size_t)o*1152 + kk] = f2bf(v);
  } else {
    int rem = idx - 294912;
    int w = rem >> 14, r3 = rem & 16383;
    int k = r3 >> 7, o = r3 & 127;
    const float* sp = (w == 0) ? W0 : (w == 1 ? W1 : fcW);
    Btw[w*16384 + o*128 + k] = f2bf(sp[r3]);
  }
}

// ---------------- small utility kernels ----------------
__global__ void fill_i32(int* p, int v, int n) {
  int i = blockIdx.x*blockDim.x + threadIdx.x;
  if (i < n) p[i] = v;
}
__global__ void edge_count(const int* __restrict__ dst, const int* __restrict__ et, int* __restrict__ cnt) {
  int e = blockIdx.x*blockDim.x + threadIdx.x;
  if (e < NEDGE) atomicAdd(&cnt[(et[e] << 16) + dst[e]], 1);
}
__global__ void cvt_bf16_2(const float* __restrict__ s0, const float* __restrict__ s1,
                           u16* __restrict__ dst) {
  int i = blockIdx.x*256 + threadIdx.x;
  const int half = 32768*Hd/4;
  const float* s = (i < half) ? s0 : s1;
  int ii = (i < half) ? i : i - half;
  float4 v = *reinterpret_cast<const float4*>(s + (size_t)ii*4);
  *reinterpret_cast<uint2*>(dst + (size_t)i*4) = make_uint2(pack2(v.x, v.y), pack2(v.z, v.w));
}

// ---------------- CSR build (rel-major segments: seg = (et<<16)|dst) ----------------
__global__ void scan1_k(const int* __restrict__ cnt, int* __restrict__ partial, int* __restrict__ bsum) {
  __shared__ int sh[256];
  int t = threadIdx.x;
  int i = blockIdx.x*256 + t;
  int v = cnt[i];
  sh[t] = v; __syncthreads();
  for (int off = 1; off < 256; off <<= 1) {
    int u = (t >= off) ? sh[t-off] : 0;
    __syncthreads();
    sh[t] += u;
    __syncthreads();
  }
  partial[i] = sh[t] - v;
  if (t == 255) bsum[blockIdx.x] = sh[255];
}
__global__ void scan2_k(int* __restrict__ bsum) {
  __shared__ int sh[256];
  int t = threadIdx.x;
  int v0 = bsum[t*4+0], v1 = bsum[t*4+1], v2 = bsum[t*4+2], v3 = bsum[t*4+3];
  int tot = v0+v1+v2+v3;
  sh[t] = tot; __syncthreads();
  for (int off = 1; off < 256; off <<= 1) {
    int u = (t >= off) ? sh[t-off] : 0;
    __syncthreads();
    sh[t] += u;
    __syncthreads();
  }
  int base = sh[t] - tot;
  bsum[t*4+0] = base;
  bsum[t*4+1] = base + v0;
  bsum[t*4+2] = base + v0+v1;
  bsum[t*4+3] = base + v0+v1+v2;
}
__global__ void scan3_k(const int* __restrict__ partial, const int* __restrict__ bsum, int* __restrict__ offsets) {
  int i = blockIdx.x*256 + threadIdx.x;
  offsets[i] = partial[i] + bsum[i >> 8];
  if (i == 0) offsets[NRSEG] = NEDGE;
}
__global__ void csr_fill(const int* __restrict__ src, const int* __restrict__ dst,
                         const int* __restrict__ et, const int* __restrict__ offsets,
                         int* __restrict__ fillctr, u32* __restrict__ meta) {
  int e = blockIdx.x*blockDim.x + threadIdx.x;
  if (e >= NEDGE) return;
  int d = dst[e];
  int seg = (et[e] << 16) + d;
  int pos = offsets[seg] + atomicAdd(&fillctr[seg], 1);
  meta[pos] = (u32)src[e];          // high bits filled with alpha by seg_alpha
}

// ---------------- attention scalar path ----------------
__global__ void qkvec_all(const float* __restrict__ attW, const float* __restrict__ att_q,
                          const float* __restrict__ att_k,
                          float* __restrict__ qvecL, float* __restrict__ kvecL) {
  int l = blockIdx.x;
  const float* aW = attW + (size_t)l*16*Hd*Hd;
  const float* aq = att_q + (size_t)l*16*Hd;
  const float* ak = att_k + (size_t)l*16*Hd;
  int r = threadIdx.x >> 7, h = threadIdx.x & 127;
  const float* wrow = aW + ((size_t)r*Hd + h)*Hd;
  const float* qv = aq + (size_t)r*Hd;
  const float* kv = ak + (size_t)r*Hd;
  float sq_ = 0.f, sk_ = 0.f;
  for (int o = 0; o < Hd; ++o) { float w = wrow[o]; sq_ = fmaf(w, qv[o], sq_); sk_ = fmaf(w, kv[o], sk_); }
  qvecL[l*512 + r*Hd + h] = sq_;
  kvecL[l*512 + r*Hd + h] = sk_;
}

// one wave per node: produce xmb (bf16) AND per-rel attention scalars sq/sk.
// MODE 0: xb = rm * x_in; MODE 1: xb = rm * leaky(bn(h)); MODE 2: xb = leaky(bn(h)) + x_in
// Modes 1/2 compute BN scale/shift per-thread from raw sums (bns/g/b) - no bn_final kernel.
template<int MODE>
__global__ __launch_bounds__(256) void xform_sqk(
    const float* __restrict__ hin, const float* __restrict__ bns,
    const float* __restrict__ bn_g, const float* __restrict__ bn_b,
    const float* __restrict__ mask, const float* __restrict__ x_in,
    const float* __restrict__ qvec, const float* __restrict__ kvec,
    u16* __restrict__ xmb, float* __restrict__ sq, float* __restrict__ sk)
{
  int n = blockIdx.x*4 + (threadIdx.x >> 6);
  int lane = threadIdx.x & 63;
  float2 v = *(const float2*)(hin + (size_t)n*Hd + lane*2);
  if (MODE != 0) {
    int c = lane*2;
    float2 s1 = *(const float2*)(bns + c);
    float2 s2 = *(const float2*)(bns + 128 + c);
    float2 gg = *(const float2*)(bn_g + c);
    float2 bb = *(const float2*)(bn_b + c);
    float mux = s1.x * (1.f/NTOT), muy = s1.y * (1.f/NTOT);
    float vax = s2.x * (1.f/NTOT) - mux*mux;
    float vay = s2.y * (1.f/NTOT) - muy*muy;
    float scx = gg.x * __frsqrt_rn(vax + 1e-5f);
    float scy = gg.y * __frsqrt_rn(vay + 1e-5f);
    float shx = bb.x - mux*scx;
    float shy = bb.y - muy*scy;
    v.x = fmaf(v.x, scx, shx); v.y = fmaf(v.y, scy, shy);
    v.x = v.x >= 0.f ? v.x : 0.01f*v.x;
    v.y = v.y >= 0.f ? v.y : 0.01f*v.y;
  }
  float2 xb;
  if (MODE == 2) {
    float2 rs = *(const float2*)(x_in + (size_t)n*Hd + lane*2);
    xb.x = v.x + rs.x; xb.y = v.y + rs.y;
  } else {
    float s = mask[(size_t)n*Hd];          // row-constant mask
    xb.x = v.x*s; xb.y = v.y*s;
  }
  *(u32*)(xmb + (size_t)n*Hd + lane*2) = pack2(xb.x, xb.y);
  if (MODE != 2) {
    float pq[RREL], pk[RREL];
#pragma unroll
    for (int r = 0; r < RREL; ++r) {
      float2 q = *(const float2*)(qvec + r*Hd + lane*2);
      float2 k = *(const float2*)(kvec + r*Hd + lane*2);
      pq[r] = xb.x*q.x + xb.y*q.y;
      pk[r] = xb.x*k.x + xb.y*k.y;
    }
#pragma unroll
    for (int off = 32; off > 0; off >>= 1)
#pragma unroll
      for (int r = 0; r < RREL; ++r) {
        pq[r] += __shfl_xor(pq[r], off);
        pk[r] += __shfl_xor(pk[r], off);
      }
    if (lane == 0)
#pragma unroll
      for (int r = 0; r < RREL; ++r) {
        sq[(size_t)r*NTOT + n] = pq[r];
        sk[(size_t)r*NTOT + n] = pk[r];
      }
  }
}

// one thread per segment: softmax within segment (logits bounded -> no max-subtract).
// pass 1: store bf16(exp) in meta high bits, sum in f32; pass 2: rescale in place.
// Block 0 zeroes bns (safe: runs after the previous layer's xform consumed bns).
__global__ void seg_alpha(u32* __restrict__ meta, const int* __restrict__ offsets,
                          const float* __restrict__ sq, const float* __restrict__ sk,
                          float* __restrict__ bns) {
  if (blockIdx.x == 0) bns[threadIdx.x] = 0.f;
  int seg = blockIdx.x*256 + threadIdx.x;
  int e0 = offsets[seg], e1 = offsets[seg+1];
  if (e0 == e1) return;
  const float* skr = sk + (seg & 0xFFFF0000u);   // + r*NTOT
  float sqv = sq[seg];
  float sum = 0.f;
  for (int e = e0; e < e1; ++e) {
    u32 m = meta[e];
    float lg = sqv + skr[m & 0xffffu];
    lg = lg >= 0.f ? lg : 0.2f*lg;
    float ex = __expf(lg);
    sum += ex;
    meta[e] = (m & 0xffffu) | ((u32)f2bf(ex) << 16);
  }
  float inv = 1.f / fmaxf(sum, 1e-16f);
  for (int e = e0; e < e1; ++e) {
    u32 m = meta[e];
    float a = __uint_as_float(m & 0xffff0000u) * inv;
    meta[e] = (m & 0xffffu) | ((u32)f2bf(a) << 16);
  }
}

extern "C" void kernel_launch(void* const* d_in, const int* in_sizes, int n_in,
                              void* d_out, int out_size, void* d_ws, size_t ws_size,
                              hipStream_t stream) {
  const float* x0       = (const float*)d_in[0];
  const float* x1       = (const float*)d_in[1];
  const float* W0       = (const float*)d_in[2];
  const float* b0       = (const float*)d_in[3];
  const float* W1       = (const float*)d_in[4];
  const float* b1       = (const float*)d_in[5];
  const float* mask     = (const float*)d_in[6];
  const float* conv_root= (const float*)d_in[7];
  const float* conv_rel = (const float*)d_in[8];
  const float* attW     = (const float*)d_in[10];
  const float* att_q    = (const float*)d_in[11];
  const float* att_k    = (const float*)d_in[12];
  const float* bn_g     = (const float*)d_in[14];
  const float* bn_b     = (const float*)d_in[15];
  const float* fc_W     = (const float*)d_in[16];
  const float* fc_b     = (const float*)d_in[17];
  const int* edge_index = (const int*)d_in[18];
  const int* edge_type  = (const int*)d_in[19];
  const int* src = edge_index;
  const int* dst = edge_index + NEDGE;
  (void)in_sizes; (void)n_in; (void)out_size; (void)ws_size;

  char* ws = (char*)d_ws;
  size_t off = 0;
  auto alloc = [&](size_t bytes) { void* p = ws + off; off = (off + bytes + 255) & ~(size_t)255; return p; };
  float* x_in  = (float*)alloc((size_t)NTOT*Hd*4);
  float* hbuf  = (float*)alloc((size_t)NTOT*Hd*4);
  u16*   xmb   = (u16*)  alloc((size_t)NTOT*Hd*2);
  float* sq    = (float*)alloc((size_t)RREL*NTOT*4);
  float* sk    = (float*)alloc((size_t)RREL*NTOT*4);
  int* cnt     = (int*)alloc((size_t)NRSEG*4);
  int* fillctr = (int*)alloc((size_t)NRSEG*4);    // contiguous with cnt
  int* partial = (int*)alloc((size_t)NRSEG*4);
  int* offsets = (int*)alloc((size_t)(NRSEG+4)*4);
  int* bsum    = (int*)alloc(4096);
  u32* meta    = (u32*)alloc((size_t)(NEDGE+16)*4);     // +16 pad for head over-read
  float* qvecL = (float*)alloc(2*512*4);
  float* kvecL = (float*)alloc(2*512*4);
  float* bns    = (float*)alloc(1024);
  u16* Btw  = (u16*)alloc((size_t)3*128*128*2);   // W0^T | W1^T | fc^T
  u16* Btg0 = (u16*)alloc((size_t)128*1152*2);
  u16* Btg1 = (u16*)alloc((size_t)128*1152*2);
  u16* BtgL[2] = {Btg0, Btg1};

  // ---- static CSR (rel-major segments) ----
  fill_i32<<<2*NRSEG/256, 256, 0, stream>>>(cnt, 0, 2*NRSEG);   // cnt + fillctr
  edge_count<<<NEDGE/256, 256, 0, stream>>>(dst, edge_type, cnt);
  scan1_k<<<NRSEG/256, 256, 0, stream>>>(cnt, partial, bsum);
  scan2_k<<<1, 256, 0, stream>>>(bsum);
  scan3_k<<<NRSEG/256, 256, 0, stream>>>(partial, bsum, offsets);
  csr_fill<<<NEDGE/256, 256, 0, stream>>>(src, dst, edge_type, offsets, fillctr, meta);

  // ---- all weights transposed/converted in one dispatch; qvec/kvec both layers ----
  wtrans_all<<<1344, 256, 0, stream>>>(conv_rel, attW, conv_root, W0, W1, fc_W,
                                       Btg0, Btg1, Btw);
  qkvec_all<<<2, 512, 0, stream>>>(attW, att_q, att_k, qvecL, kvecL);

  // ---- x_in = [x0@W0+b0 ; x1@W1+b1]; xmb = bf16(rm*x_in) + sq/sk(layer0) ----
  cvt_bf16_2<<<(NTOT*Hd/4)/256, 256, 0, stream>>>(x0, x1, xmb);
  mgemm<3><<<512, 256, 0, stream>>>(xmb, Hd, Btw, 128, b0, b1, x_in, 128);
  xform_sqk<0><<<NTOT/4, 256, 0, stream>>>(x_in, nullptr, nullptr, nullptr, mask, nullptr,
                                           qvecL, kvecL, xmb, sq, sk);

  for (int l = 0; l < 2; ++l) {
    seg_alpha<<<NRSEG/256, 256, 0, stream>>>(meta, offsets, sq, sk, bns);
    fused_gemm<<<NTOT/64, 512, 0, stream>>>(xmb, meta, offsets, BtgL[l], hbuf, bns);
    if (l == 0)
      xform_sqk<1><<<NTOT/4, 256, 0, stream>>>(hbuf, bns, bn_g, bn_b, mask, nullptr,
                                               qvecL + 512, kvecL + 512, xmb, sq, sk);
    else
      xform_sqk<2><<<NTOT/4, 256, 0, stream>>>(hbuf, bns, bn_g + Hd, bn_b + Hd, nullptr, x_in,
                                               nullptr, nullptr, xmb, sq, sk);
  }

  // out = (x + x_in) @ fc_W + fc_b, remapped rows
  mgemm<2><<<512, 256, 0, stream>>>(xmb, Hd, Btw + 2*16384, 128, fc_b, nullptr,
                                    (float*)d_out, 128);
}

// Round 17
// 425.690 us; speedup vs baseline: 1.0935x; 1.0005x over previous
//
#include <hip/hip_runtime.h>

#define Hd 128
#define NTOT 65536
#define RREL 4
#define NRSEG (NTOT*RREL)
#define NEDGE 524288

typedef unsigned short u16;
typedef unsigned int u32;
typedef short bf16x8 __attribute__((ext_vector_type(8)));
typedef float f32x4 __attribute__((ext_vector_type(4)));

__device__ __forceinline__ u16 f2bf(float f) {   // RNE
  u32 u = __float_as_uint(f);
  return (u16)((u + 0x7fffu + ((u >> 16) & 1u)) >> 16);
}
__device__ __forceinline__ u32 pack2(float lo, float hi) {
  return ((u32)f2bf(hi) << 16) | f2bf(lo);
}

// swizzled byte offset within a [rows][256 B] bf16 LDS tile (involution on bits 7:4)
__device__ __forceinline__ int swzb(int row, int o) {
  return (row*256 + o) ^ ((row & 15) << 4);
}

// ======== mgemm: C[M,128] = A[M,K] @ Bt[128,K]^T (128-row tiles, 256 thr) ========
__device__ __forceinline__ void stage_tile(const u16* __restrict__ g, int ld,
                                           u16* lds, int wave, int lane) {
#pragma unroll
  for (int t = 0; t < 2; ++t) {
    int i = wave*2 + t;
    int row = i*16 + (lane >> 2);
    int col16 = (lane & 3) ^ ((lane >> 3) & 3);
    const u16* src = g + (size_t)row*ld + col16*8;
    __builtin_amdgcn_global_load_lds((const __attribute__((address_space(1))) void*)src,
                                     (__attribute__((address_space(3))) void*)(lds + i*512),
                                     16, 0, 0);
  }
}

// CMODE 2: remapped final-output write (+bias);
// CMODE 3: dual half-M (blocks >= gridDim/2 use A+32768 rows, Bt+128*128, bias2, C+32768 rows)
template<int CMODE>
__global__ __launch_bounds__(256) void mgemm(const u16* __restrict__ A, int lda,
                                             const u16* __restrict__ Bt, int ldb,
                                             const float* __restrict__ bias,
                                             const float* __restrict__ bias2,
                                             float* __restrict__ C, int kTot)
{
  __shared__ u16 As[4096], Bs[4096];
  const int tid = threadIdx.x, wave = tid >> 6, lane = tid & 63;
  const int wm = wave >> 1, wn = wave & 1;
  int bx = blockIdx.x;
  if (CMODE == 3) {
    if (bx >= (int)gridDim.x/2) {
      bx -= gridDim.x/2;
      A += (size_t)32768*lda; Bt += 128*128; bias = bias2; C += (size_t)32768*Hd;
    }
  }
  const int brow = bx * 128;
  const u16* Ab = A + (size_t)brow*lda;
  f32x4 acc[4][4];
#pragma unroll
  for (int i = 0; i < 4; ++i)
#pragma unroll
    for (int j = 0; j < 4; ++j) acc[i][j] = (f32x4){0.f, 0.f, 0.f, 0.f};

  const int ks = (lane >> 4) * 16;
  const int rl = lane & 15;
  for (int k0 = 0; k0 < kTot; k0 += 32) {
    stage_tile(Ab + k0, lda, As, wave, lane);
    stage_tile(Bt + k0, ldb, Bs, wave, lane);
    __syncthreads();
    bf16x8 af[4], bv[4];
    const char* Ac = (const char*)As;
    const char* Bc = (const char*)Bs;
#pragma unroll
    for (int i = 0; i < 4; ++i) {
      int r = wm*64 + i*16 + rl;
      int by = (r*64 + ks) ^ (((r >> 1) & 3) << 4);
      af[i] = *(const bf16x8*)(Ac + by);
    }
#pragma unroll
    for (int j = 0; j < 4; ++j) {
      int r = wn*64 + j*16 + rl;
      int by = (r*64 + ks) ^ (((r >> 1) & 3) << 4);
      bv[j] = *(const bf16x8*)(Bc + by);
    }
#pragma unroll
    for (int i = 0; i < 4; ++i)
#pragma unroll
      for (int j = 0; j < 4; ++j)
        acc[i][j] = __builtin_amdgcn_mfma_f32_16x16x32_bf16(af[i], bv[j], acc[i][j], 0, 0, 0);
    __syncthreads();
  }
  const int cl = lane & 15;
  const int rq = (lane >> 4) * 4;
#pragma unroll
  for (int i = 0; i < 4; ++i) {
#pragma unroll
    for (int q = 0; q < 4; ++q) {
      int row = brow + wm*64 + i*16 + rq + q;
      size_t ob;
      if (CMODE == 2) {
        int b = row >> 6, p = row & 63;
        ob = (p == 0) ? (size_t)b*Hd
                      : (size_t)(1024*Hd) + ((size_t)(b*63 + (p-1)))*Hd;
      } else {
        ob = (size_t)row * Hd;
      }
#pragma unroll
      for (int j = 0; j < 4; ++j) {
        int col = wn*64 + j*16 + cl;
        float v = acc[i][j][q];
        if (bias) v += bias[col];
        C[ob + col] = v;
      }
    }
  }
}

// ======== fused register-gather + K=1152 GEMM + BN-stats (64-row tile, 80 KB) ========
// meta[e] = src | (bf16(alpha) << 16)  (alpha pre-normalized by seg_alpha)
// Btg: bf16 [128 out][1152], chunks: 0..3 conv_rel r, 4..7 attW r, 8 conv_root
// Double-buffered weights: every stageB issued one phase early, hidden under
// gather / mfma; no naked weight-stage stalls.
__device__ __forceinline__ void stageB(const u16* __restrict__ gbase, int ld,
                                       u16* lds, int wave, int lane) {
#pragma unroll
  for (int t = 0; t < 4; ++t) {
    int ti = wave*4 + t;
    int row = ti*4 + (lane >> 4);
    int lchunk = (lane & 15) ^ (row & 15);
    const u16* src = gbase + (size_t)row*ld + lchunk*8;
    __builtin_amdgcn_global_load_lds((const __attribute__((address_space(1))) void*)src,
                                     (__attribute__((address_space(3))) void*)(lds + ti*512),
                                     16, 0, 0);
  }
}
// stage 64 rows x 256B (16 KB) with 8 waves
__device__ __forceinline__ void stageY64(const u16* __restrict__ gbase, int ld,
                                         u16* lds, int wave, int lane) {
#pragma unroll
  for (int t = 0; t < 2; ++t) {
    int ti = wave*2 + t;
    int row = ti*4 + (lane >> 4);
    int lchunk = (lane & 15) ^ (row & 15);
    const u16* src = gbase + (size_t)row*ld + lchunk*8;
    __builtin_amdgcn_global_load_lds((const __attribute__((address_space(1))) void*)src,
                                     (__attribute__((address_space(3))) void*)(lds + ti*512),
                                     16, 0, 0);
  }
}

__device__ __forceinline__ void mfma64(const u16* Yt, const u16* Bt, f32x4 (&acc)[2][2],
                                       int wm, int wn, int lane) {
  const int rl = lane & 15;
  const int ko = (lane >> 4) * 16;
  const char* Yc_ = (const char*)Yt;
  const char* Bc_ = (const char*)Bt;
#pragma unroll
  for (int ks = 0; ks < 4; ++ks) {
    int o = ks*64 + ko;
    bf16x8 af[2], bv[2];
#pragma unroll
    for (int i = 0; i < 2; ++i)
      af[i] = *(const bf16x8*)(Yc_ + swzb(wm*32 + i*16 + rl, o));
#pragma unroll
    for (int j = 0; j < 2; ++j)
      bv[j] = *(const bf16x8*)(Bc_ + swzb(wn*32 + j*16 + rl, o));
#pragma unroll
    for (int i = 0; i < 2; ++i)
#pragma unroll
      for (int j = 0; j < 2; ++j)
        acc[i][j] = __builtin_amdgcn_mfma_f32_16x16x32_bf16(af[i], bv[j], acc[i][j], 0, 0, 0);
  }
}

__global__ __launch_bounds__(512, 4) void fused_gemm(
    const u16* __restrict__ xmb, const u32* __restrict__ meta,
    const int* __restrict__ offsets, const u16* __restrict__ Btg,
    float* __restrict__ hbuf, float* __restrict__ bns)
{
  __shared__ u16 Yt[8192];    // 16 KB: 64-row Y tile
  __shared__ u16 B0[16384];   // 32 KB: conv weights (then root)
  __shared__ u16 B1[16384];   // 32 KB: att weights
  const int tid = threadIdx.x, wave = tid >> 6, lane = tid & 63;
  const int wm = wave >> 2, wn = wave & 3;
  const int brow = blockIdx.x * 64;
  f32x4 acc[2][2];
#pragma unroll
  for (int i = 0; i < 2; ++i)
#pragma unroll
    for (int j = 0; j < 2; ++j) acc[i][j] = (f32x4){0.f,0.f,0.f,0.f};

  u32 axp[8];                 // att sums, packed bf16

  stageB(Btg + 0*128, 1152, B0, wave, lane);   // rel-0 conv, hidden under gather(0)
  stageB(Btg + 4*128, 1152, B1, wave, lane);   // rel-0 att

#pragma unroll
  for (int r = 0; r < RREL; ++r) {
    const int segBase = (r << 16) + brow;      // rel-major segments
    // ---- gather (long): all in-flight stages hide under this ----
#pragma unroll
    for (int g = 0; g < 4; ++g) {              // 4 groups x 2 nodes per wave
      int ln0 = wave*8 + g*2;
      int e0[2], ct[2];
#pragma unroll
      for (int m = 0; m < 2; ++m) {
        int seg = segBase + ln0 + m;
        e0[m] = offsets[seg];
        ct[m] = offsets[seg+1] - e0[m];
      }
      u32 mm[2][4];                            // src | alpha-bf16<<16 (broadcast loads)
#pragma unroll
      for (int m = 0; m < 2; ++m)
#pragma unroll
        for (int k = 0; k < 4; ++k)
          mm[m][k] = meta[e0[m] + k];          // padded; junk if k>=ct
      u32 uu[2][4];
#pragma unroll
      for (int m = 0; m < 2; ++m)
#pragma unroll
        for (int k = 0; k < 4; ++k) {
          int sx = (k < ct[m]) ? (int)(mm[m][k] & 0xffffu) : 0;   // clamp to L1-hot row
          uu[m][k] = *(const u32*)(xmb + ((size_t)sx << 7) + lane*2);
        }
      float cx[2], cy[2], ax[2], ay[2];
#pragma unroll
      for (int m = 0; m < 2; ++m) { cx[m]=cy[m]=ax[m]=ay[m]=0.f; }
#pragma unroll
      for (int m = 0; m < 2; ++m) {
#pragma unroll
        for (int k = 0; k < 4; ++k) {
          float pr = (k < ct[m]) ? 1.f : 0.f;
          float al = pr * __uint_as_float(mm[m][k] & 0xffff0000u);  // bf16 alpha
          float vx = __uint_as_float(uu[m][k] << 16);
          float vy = __uint_as_float(uu[m][k] & 0xffff0000u);
          cx[m] = fmaf(pr, vx, cx[m]);
          cy[m] = fmaf(pr, vy, cy[m]);
          ax[m] = fmaf(al, vx, ax[m]);
          ay[m] = fmaf(al, vy, ay[m]);
        }
        for (int e = e0[m] + 4; e < e0[m] + ct[m]; ++e) {   // rare tail
          u32 m2 = meta[e];
          int s = (int)(m2 & 0xffffu);
          float al = __uint_as_float(m2 & 0xffff0000u);
          u32 u = *(const u32*)(xmb + ((size_t)s << 7) + lane*2);
          float vx = __uint_as_float(u << 16);
          float vy = __uint_as_float(u & 0xffff0000u);
          cx[m] += vx; cy[m] += vy;
          ax[m] = fmaf(al, vx, ax[m]);
          ay[m] = fmaf(al, vy, ay[m]);
        }
      }
#pragma unroll
      for (int m = 0; m < 2; ++m) {
        int ln = ln0 + m;
        float ic = 1.f / (float)max(ct[m], 1);
        *(u32*)((char*)Yt + swzb(ln, lane*4)) = pack2(cx[m]*ic, cy[m]*ic);
        axp[g*2+m] = pack2(ax[m], ay[m]);
      }
    }
    __syncthreads();                           // Yt conv written; B0,B1 staged
    mfma64(Yt, B0, acc, wm, wn, lane);         // conv contribution
    __syncthreads();                           // conv reads of Yt/B0 done
    if (r < 3) stageB(Btg + (r+1)*128, 1152, B0, wave, lane);  // next conv
    else       stageB(Btg + 8*128,     1152, B0, wave, lane);  // root
#pragma unroll
    for (int g = 0; g < 4; ++g)
#pragma unroll
      for (int m = 0; m < 2; ++m) {
        int ln = wave*8 + g*2 + m;
        *(u32*)((char*)Yt + swzb(ln, lane*4)) = axp[g*2+m];
      }
    __syncthreads();                           // Yt att written (B1 long ready)
    mfma64(Yt, B1, acc, wm, wn, lane);         // att contribution
    __syncthreads();                           // att reads of Yt/B1 done
    if (r < 3) stageB(Btg + (4+r+1)*128, 1152, B1, wave, lane); // next att (hides under gather)
  }
  // ---- root chunk: Y = xmb tile (B0=root already in flight) ----
  stageY64(xmb + ((size_t)brow << 7), Hd, Yt, wave, lane);
  __syncthreads();
  mfma64(Yt, B0, acc, wm, wn, lane);

  // ---- epilogue: write hbuf + BN partial sums ----
  const int cl = lane & 15, rq = (lane >> 4) * 4;
#pragma unroll
  for (int j = 0; j < 2; ++j) {
    float s = 0.f, s2 = 0.f;
#pragma unroll
    for (int i = 0; i < 2; ++i) {
#pragma unroll
      for (int q = 0; q < 4; ++q) {
        float v = acc[i][j][q];
        int row = brow + wm*32 + i*16 + rq + q;
        hbuf[(size_t)row*Hd + wn*32 + j*16 + cl] = v;
        s += v; s2 = fmaf(v, v, s2);
      }
    }
    s  += __shfl_xor(s, 16);  s  += __shfl_xor(s, 32);
    s2 += __shfl_xor(s2, 16); s2 += __shfl_xor(s2, 32);
    if (lane < 16) {
      int col = wn*32 + j*16 + cl;
      unsafeAtomicAdd(&bns[col], s);
      unsafeAtomicAdd(&bns[128 + col], s2);
    }
  }
}

// ---------------- all weight transpose+convert in one dispatch ----------------
__global__ void wtrans_all(const float* __restrict__ conv_rel, const float* __restrict__ attW,
                           const float* __restrict__ conv_root, const float* __restrict__ W0,
                           const float* __restrict__ W1, const float* __restrict__ fcW,
                           u16* __restrict__ Btg0, u16* __restrict__ Btg1, u16* __restrict__ Btw) {
  int idx = blockIdx.x*256 + threadIdx.x;
  if (idx < 294912) {
    int l = idx / 147456;
    int rem = idx - l*147456;
    u16* Btg = l ? Btg1 : Btg0;
    float v; int o, kk;
    if (rem < 65536)       { o = rem & 127; kk = rem >> 7;               v = conv_rel[(size_t)l*65536 + rem]; }
    else if (rem < 131072) { int r2 = rem - 65536; o = r2 & 127; kk = 512 + (r2 >> 7); v = attW[(size_t)l*262144 + r2]; }
    else                   { int r3 = rem - 131072; o = r3 & 127; kk = 1024 + (r3 >> 7); v = conv_root[(size_t)l*16384 + r3]; }
    Btg[(size_t)o*1152 + kk] = f2bf(v);
  } else {
    int rem = idx - 294912;
    int w = rem >> 14, r3 = rem & 16383;
    int k = r3 >> 7, o = r3 & 127;
    const float* sp = (w == 0) ? W0 : (w == 1 ? W1 : fcW);
    Btw[w*16384 + o*128 + k] = f2bf(sp[r3]);
  }
}

// ---------------- small utility kernels ----------------
__global__ void fill_i32(int* p, int v, int n) {
  int i = blockIdx.x*blockDim.x + threadIdx.x;
  if (i < n) p[i] = v;
}
__global__ void edge_count(const int* __restrict__ dst, const int* __restrict__ et, int* __restrict__ cnt) {
  int e = blockIdx.x*blockDim.x + threadIdx.x;
  if (e < NEDGE) atomicAdd(&cnt[(et[e] << 16) + dst[e]], 1);
}
__global__ void cvt_bf16_2(const float* __restrict__ s0, const float* __restrict__ s1,
                           u16* __restrict__ dst) {
  int i = blockIdx.x*256 + threadIdx.x;
  const int half = 32768*Hd/4;
  const float* s = (i < half) ? s0 : s1;
  int ii = (i < half) ? i : i - half;
  float4 v = *reinterpret_cast<const float4*>(s + (size_t)ii*4);
  *reinterpret_cast<uint2*>(dst + (size_t)i*4) = make_uint2(pack2(v.x, v.y), pack2(v.z, v.w));
}

// ---------------- CSR build (rel-major segments: seg = (et<<16)|dst) ----------------
__global__ void scan1_k(const int* __restrict__ cnt, int* __restrict__ partial, int* __restrict__ bsum) {
  __shared__ int sh[256];
  int t = threadIdx.x;
  int i = blockIdx.x*256 + t;
  int v = cnt[i];
  sh[t] = v; __syncthreads();
  for (int off = 1; off < 256; off <<= 1) {
    int u = (t >= off) ? sh[t-off] : 0;
    __syncthreads();
    sh[t] += u;
    __syncthreads();
  }
  partial[i] = sh[t] - v;
  if (t == 255) bsum[blockIdx.x] = sh[255];
}
__global__ void scan2_k(int* __restrict__ bsum) {
  __shared__ int sh[256];
  int t = threadIdx.x;
  int v0 = bsum[t*4+0], v1 = bsum[t*4+1], v2 = bsum[t*4+2], v3 = bsum[t*4+3];
  int tot = v0+v1+v2+v3;
  sh[t] = tot; __syncthreads();
  for (int off = 1; off < 256; off <<= 1) {
    int u = (t >= off) ? sh[t-off] : 0;
    __syncthreads();
    sh[t] += u;
    __syncthreads();
  }
  int base = sh[t] - tot;
  bsum[t*4+0] = base;
  bsum[t*4+1] = base + v0;
  bsum[t*4+2] = base + v0+v1;
  bsum[t*4+3] = base + v0+v1+v2;
}
__global__ void scan3_k(const int* __restrict__ partial, const int* __restrict__ bsum, int* __restrict__ offsets) {
  int i = blockIdx.x*256 + threadIdx.x;
  offsets[i] = partial[i] + bsum[i >> 8];
  if (i == 0) offsets[NRSEG] = NEDGE;
}
__global__ void csr_fill(const int* __restrict__ src, const int* __restrict__ dst,
                         const int* __restrict__ et, const int* __restrict__ offsets,
                         int* __restrict__ fillctr, u32* __restrict__ meta) {
  int e = blockIdx.x*blockDim.x + threadIdx.x;
  if (e >= NEDGE) return;
  int d = dst[e];
  int seg = (et[e] << 16) + d;
  int pos = offsets[seg] + atomicAdd(&fillctr[seg], 1);
  meta[pos] = (u32)src[e];          // high bits filled with alpha by seg_alpha
}

// ---------------- attention scalar path ----------------
__global__ void qkvec_all(const float* __restrict__ attW, const float* __restrict__ att_q,
                          const float* __restrict__ att_k,
                          float* __restrict__ qvecL, float* __restrict__ kvecL) {
  int l = blockIdx.x;
  const float* aW = attW + (size_t)l*16*Hd*Hd;
  const float* aq = att_q + (size_t)l*16*Hd;
  const float* ak = att_k + (size_t)l*16*Hd;
  int r = threadIdx.x >> 7, h = threadIdx.x & 127;
  const float* wrow = aW + ((size_t)r*Hd + h)*Hd;
  const float* qv = aq + (size_t)r*Hd;
  const float* kv = ak + (size_t)r*Hd;
  float sq_ = 0.f, sk_ = 0.f;
  for (int o = 0; o < Hd; ++o) { float w = wrow[o]; sq_ = fmaf(w, qv[o], sq_); sk_ = fmaf(w, kv[o], sk_); }
  qvecL[l*512 + r*Hd + h] = sq_;
  kvecL[l*512 + r*Hd + h] = sk_;
}

// one wave per node: produce xmb (bf16) AND per-rel attention scalars sq/sk.
// MODE 0: xb = rm * x_in; MODE 1: xb = rm * leaky(bn(h)); MODE 2: xb = leaky(bn(h)) + x_in
// Modes 1/2 compute BN scale/shift per-thread from raw sums (bns/g/b) - no bn_final kernel.
template<int MODE>
__global__ __launch_bounds__(256) void xform_sqk(
    const float* __restrict__ hin, const float* __restrict__ bns,
    const float* __restrict__ bn_g, const float* __restrict__ bn_b,
    const float* __restrict__ mask, const float* __restrict__ x_in,
    const float* __restrict__ qvec, const float* __restrict__ kvec,
    u16* __restrict__ xmb, float* __restrict__ sq, float* __restrict__ sk)
{
  int n = blockIdx.x*4 + (threadIdx.x >> 6);
  int lane = threadIdx.x & 63;
  float2 v = *(const float2*)(hin + (size_t)n*Hd + lane*2);
  if (MODE != 0) {
    int c = lane*2;
    float2 s1 = *(const float2*)(bns + c);
    float2 s2 = *(const float2*)(bns + 128 + c);
    float2 gg = *(const float2*)(bn_g + c);
    float2 bb = *(const float2*)(bn_b + c);
    float mux = s1.x * (1.f/NTOT), muy = s1.y * (1.f/NTOT);
    float vax = s2.x * (1.f/NTOT) - mux*mux;
    float vay = s2.y * (1.f/NTOT) - muy*muy;
    float scx = gg.x * __frsqrt_rn(vax + 1e-5f);
    float scy = gg.y * __frsqrt_rn(vay + 1e-5f);
    float shx = bb.x - mux*scx;
    float shy = bb.y - muy*scy;
    v.x = fmaf(v.x, scx, shx); v.y = fmaf(v.y, scy, shy);
    v.x = v.x >= 0.f ? v.x : 0.01f*v.x;
    v.y = v.y >= 0.f ? v.y : 0.01f*v.y;
  }
  float2 xb;
  if (MODE == 2) {
    float2 rs = *(const float2*)(x_in + (size_t)n*Hd + lane*2);
    xb.x = v.x + rs.x; xb.y = v.y + rs.y;
  } else {
    float s = mask[(size_t)n*Hd];          // row-constant mask
    xb.x = v.x*s; xb.y = v.y*s;
  }
  *(u32*)(xmb + (size_t)n*Hd + lane*2) = pack2(xb.x, xb.y);
  if (MODE != 2) {
    float pq[RREL], pk[RREL];
#pragma unroll
    for (int r = 0; r < RREL; ++r) {
      float2 q = *(const float2*)(qvec + r*Hd + lane*2);
      float2 k = *(const float2*)(kvec + r*Hd + lane*2);
      pq[r] = xb.x*q.x + xb.y*q.y;
      pk[r] = xb.x*k.x + xb.y*k.y;
    }
#pragma unroll
    for (int off = 32; off > 0; off >>= 1)
#pragma unroll
      for (int r = 0; r < RREL; ++r) {
        pq[r] += __shfl_xor(pq[r], off);
        pk[r] += __shfl_xor(pk[r], off);
      }
    if (lane == 0)
#pragma unroll
      for (int r = 0; r < RREL; ++r) {
        sq[(size_t)r*NTOT + n] = pq[r];
        sk[(size_t)r*NTOT + n] = pk[r];
      }
  }
}

// one thread per segment: softmax within segment (logits bounded -> no max-subtract).
// pass 1: store bf16(exp) in meta high bits, sum in f32; pass 2: rescale in place.
// Block 0 zeroes bns (safe: runs after the previous layer's xform consumed bns).
__global__ void seg_alpha(u32* __restrict__ meta, const int* __restrict__ offsets,
                          const float* __restrict__ sq, const float* __restrict__ sk,
                          float* __restrict__ bns) {
  if (blockIdx.x == 0) bns[threadIdx.x] = 0.f;
  int seg = blockIdx.x*256 + threadIdx.x;
  int e0 = offsets[seg], e1 = offsets[seg+1];
  if (e0 == e1) return;
  const float* skr = sk + (seg & 0xFFFF0000u);   // + r*NTOT
  float sqv = sq[seg];
  float sum = 0.f;
  for (int e = e0; e < e1; ++e) {
    u32 m = meta[e];
    float lg = sqv + skr[m & 0xffffu];
    lg = lg >= 0.f ? lg : 0.2f*lg;
    float ex = __expf(lg);
    sum += ex;
    meta[e] = (m & 0xffffu) | ((u32)f2bf(ex) << 16);
  }
  float inv = 1.f / fmaxf(sum, 1e-16f);
  for (int e = e0; e < e1; ++e) {
    u32 m = meta[e];
    float a = __uint_as_float(m & 0xffff0000u) * inv;
    meta[e] = (m & 0xffffu) | ((u32)f2bf(a) << 16);
  }
}

extern "C" void kernel_launch(void* const* d_in, const int* in_sizes, int n_in,
                              void* d_out, int out_size, void* d_ws, size_t ws_size,
                              hipStream_t stream) {
  const float* x0       = (const float*)d_in[0];
  const float* x1       = (const float*)d_in[1];
  const float* W0       = (const float*)d_in[2];
  const float* b0       = (const float*)d_in[3];
  const float* W1       = (const float*)d_in[4];
  const float* b1       = (const float*)d_in[5];
  const float* mask     = (const float*)d_in[6];
  const float* conv_root= (const float*)d_in[7];
  const float* conv_rel = (const float*)d_in[8];
  const float* attW     = (const float*)d_in[10];
  const float* att_q    = (const float*)d_in[11];
  const float* att_k    = (const float*)d_in[12];
  const float* bn_g     = (const float*)d_in[14];
  const float* bn_b     = (const float*)d_in[15];
  const float* fc_W     = (const float*)d_in[16];
  const float* fc_b     = (const float*)d_in[17];
  const int* edge_index = (const int*)d_in[18];
  const int* edge_type  = (const int*)d_in[19];
  const int* src = edge_index;
  const int* dst = edge_index + NEDGE;
  (void)in_sizes; (void)n_in; (void)out_size; (void)ws_size;

  char* ws = (char*)d_ws;
  size_t off = 0;
  auto alloc = [&](size_t bytes) { void* p = ws + off; off = (off + bytes + 255) & ~(size_t)255; return p; };
  float* x_in  = (float*)alloc((size_t)NTOT*Hd*4);
  float* hbuf  = (float*)alloc((size_t)NTOT*Hd*4);
  u16*   xmb   = (u16*)  alloc((size_t)NTOT*Hd*2);
  float* sq    = (float*)alloc((size_t)RREL*NTOT*4);
  float* sk    = (float*)alloc((size_t)RREL*NTOT*4);
  int* cnt     = (int*)alloc((size_t)NRSEG*4);
  int* fillctr = (int*)alloc((size_t)NRSEG*4);    // contiguous with cnt
  int* partial = (int*)alloc((size_t)NRSEG*4);
  int* offsets = (int*)alloc((size_t)(NRSEG+4)*4);
  int* bsum    = (int*)alloc(4096);
  u32* meta    = (u32*)alloc((size_t)(NEDGE+16)*4);     // +16 pad for head over-read
  float* qvecL = (float*)alloc(2*512*4);
  float* kvecL = (float*)alloc(2*512*4);
  float* bns    = (float*)alloc(1024);
  u16* Btw  = (u16*)alloc((size_t)3*128*128*2);   // W0^T | W1^T | fc^T
  u16* Btg0 = (u16*)alloc((size_t)128*1152*2);
  u16* Btg1 = (u16*)alloc((size_t)128*1152*2);
  u16* BtgL[2] = {Btg0, Btg1};

  // ---- static CSR (rel-major segments) ----
  fill_i32<<<2*NRSEG/256, 256, 0, stream>>>(cnt, 0, 2*NRSEG);   // cnt + fillctr
  edge_count<<<NEDGE/256, 256, 0, stream>>>(dst, edge_type, cnt);
  scan1_k<<<NRSEG/256, 256, 0, stream>>>(cnt, partial, bsum);
  scan2_k<<<1, 256, 0, stream>>>(bsum);
  scan3_k<<<NRSEG/256, 256, 0, stream>>>(partial, bsum, offsets);
  csr_fill<<<NEDGE/256, 256, 0, stream>>>(src, dst, edge_type, offsets, fillctr, meta);

  // ---- all weights transposed/converted in one dispatch; qvec/kvec both layers ----
  wtrans_all<<<1344, 256, 0, stream>>>(conv_rel, attW, conv_root, W0, W1, fc_W,
                                       Btg0, Btg1, Btw);
  qkvec_all<<<2, 512, 0, stream>>>(attW, att_q, att_k, qvecL, kvecL);

  // ---- x_in = [x0@W0+b0 ; x1@W1+b1]; xmb = bf16(rm*x_in) + sq/sk(layer0) ----
  cvt_bf16_2<<<(NTOT*Hd/4)/256, 256, 0, stream>>>(x0, x1, xmb);
  mgemm<3><<<512, 256, 0, stream>>>(xmb, Hd, Btw, 128, b0, b1, x_in, 128);
  xform_sqk<0><<<NTOT/4, 256, 0, stream>>>(x_in, nullptr, nullptr, nullptr, mask, nullptr,
                                           qvecL, kvecL, xmb, sq, sk);

  for (int l = 0; l < 2; ++l) {
    seg_alpha<<<NRSEG/256, 256, 0, stream>>>(meta, offsets, sq, sk, bns);
    fused_gemm<<<NTOT/64, 512, 0, stream>>>(xmb, meta, offsets, BtgL[l], hbuf, bns);
    if (l == 0)
      xform_sqk<1><<<NTOT/4, 256, 0, stream>>>(hbuf, bns, bn_g, bn_b, mask, nullptr,
                                               qvecL + 512, kvecL + 512, xmb, sq, sk);
    else
      xform_sqk<2><<<NTOT/4, 256, 0, stream>>>(hbuf, bns, bn_g + Hd, bn_b + Hd, nullptr, x_in,
                                               nullptr, nullptr, xmb, sq, sk);
  }

  // out = (x + x_in) @ fc_W + fc_b, remapped rows
  mgemm<2><<<512, 256, 0, stream>>>(xmb, Hd, Btw + 2*16384, 128, fc_b, nullptr,
                                    (float*)d_out, 128);
}